// Round 6
// baseline (144.662 us; speedup 1.0000x reference)
//
#include <hip/hip_runtime.h>

typedef __bf16 bf16x8 __attribute__((ext_vector_type(8)));
typedef float f32x4 __attribute__((ext_vector_type(4)));
typedef unsigned short u16;
typedef u16 u16x8 __attribute__((ext_vector_type(8)));
typedef u16 u16x4 __attribute__((ext_vector_type(4)));
typedef u16 u16x2 __attribute__((ext_vector_type(2)));

__device__ __forceinline__ u16 f2bf(float f) {
    union { float f; unsigned u; } x; x.f = f;
    unsigned r = x.u + 0x7fffu + ((x.u >> 16) & 1u);
    return (u16)(r >> 16);
}
__device__ __forceinline__ bf16x8 as_bf16x8(u16x8 v) {
    return __builtin_bit_cast(bf16x8, v);
}
__device__ __forceinline__ void glds16(const void* g, void* l) {
    __builtin_amdgcn_global_load_lds(
        (const __attribute__((address_space(1))) void*)g,
        (__attribute__((address_space(3))) void*)l, 16, 0, 0);
}
// row swizzle in u16-chunk units: s8(r) = (r&7)^((r>>3)&7); swz = s8<<3 (u16 offset)
__device__ __forceinline__ int swz(int r) { return (((r & 7) ^ ((r >> 3) & 7)) << 3); }

// fp32 -> bf16, 8 elems/thread
__global__ __launch_bounds__(256) void f32bf16(const float* __restrict__ in,
                                               u16* __restrict__ out, int n8) {
    int i = blockIdx.x * 256 + threadIdx.x;
    if (i >= n8) return;
    const float4* p = (const float4*)(in + (size_t)i * 8);
    float4 a = p[0], b = p[1];
    u16x8 o;
    o[0] = f2bf(a.x); o[1] = f2bf(a.y); o[2] = f2bf(a.z); o[3] = f2bf(a.w);
    o[4] = f2bf(b.x); o[5] = f2bf(b.y); o[6] = f2bf(b.z); o[7] = f2bf(b.w);
    *(u16x8*)(out + (size_t)i * 8) = o;
}

// C[m][n] = sum_k A[m][k]*B[n][k]; A,B bf16 row-major, C fp32.
// 128x128 tile, 4 waves, BK=32, global_load_lds + 2-phase dbuf. 1-D grid,
// XCD-bijective swizzle (grid % 8 == 0), col tiles = nbx.
__global__ __launch_bounds__(256) void gemm128(const u16* __restrict__ A,
                                               const u16* __restrict__ B,
                                               float* __restrict__ C,
                                               int N, int K, int nbx) {
    __shared__ u16 As[2][4096];   // [128][32] linear, matches gload_lds lane order
    __shared__ u16 Bs[2][4096];
    const int tid = threadIdx.x, lane = tid & 63, wave = tid >> 6;
    const int cpx = gridDim.x >> 3;
    const int nid = (blockIdx.x & 7) * cpx + (blockIdx.x >> 3);
    const int m0 = (nid / nbx) << 7, n0 = (nid % nbx) << 7;
    const int wr = (wave >> 1) << 6, wc = (wave & 1) << 6;
    const int fr = lane & 15, fo = (lane >> 4) << 3;
    const int srow = tid >> 2, scol = (tid & 3) << 3;
    const u16* Ag = A + (size_t)(m0 + srow) * K + scol;
    const u16* Bg = B + (size_t)(n0 + srow) * K + scol;
    u16* AsW = &As[0][0] + (wave << 9);   // wave-uniform LDS base (+lane*16B by HW)
    u16* BsW = &Bs[0][0] + (wave << 9);
    f32x4 acc[4][4] = {};
    const int nsteps = K >> 5;
    glds16(Ag, AsW);
    glds16(Ag + (size_t)64 * K, AsW + 2048);
    glds16(Bg, BsW);
    glds16(Bg + (size_t)64 * K, BsW + 2048);
    int cur = 0;
    for (int s = 0; s < nsteps; ++s) {
        __syncthreads();   // buf[cur] staged (drains vmcnt), prev reads done
        if (s + 1 < nsteps) {
            const u16* Ap = Ag + (s + 1) * 32;
            const u16* Bp = Bg + (s + 1) * 32;
            const int nb = (cur ^ 1) << 12;
            glds16(Ap, AsW + nb);
            glds16(Ap + (size_t)64 * K, AsW + nb + 2048);
            glds16(Bp, BsW + nb);
            glds16(Bp + (size_t)64 * K, BsW + nb + 2048);
        }
        const u16* Ab = &As[cur][0];
        const u16* Bb = &Bs[cur][0];
        bf16x8 af[4], bfr[4];
        #pragma unroll
        for (int i = 0; i < 4; ++i)
            af[i] = *(const bf16x8*)(Ab + (wr + i * 16 + fr) * 32 + fo);
        #pragma unroll
        for (int i = 0; i < 4; ++i)
            bfr[i] = *(const bf16x8*)(Bb + (wc + i * 16 + fr) * 32 + fo);
        #pragma unroll
        for (int i = 0; i < 4; ++i)
            #pragma unroll
            for (int j = 0; j < 4; ++j)
                acc[i][j] = __builtin_amdgcn_mfma_f32_16x16x32_bf16(af[i], bfr[j], acc[i][j], 0, 0, 0);
        cur ^= 1;
    }
    const int cr = (lane >> 4) << 2, cc = lane & 15;
    #pragma unroll
    for (int i = 0; i < 4; ++i)
        for (int j = 0; j < 4; ++j)
            for (int r = 0; r < 4; ++r)
                C[(size_t)(m0 + wr + i * 16 + cr + r) * N + (n0 + wc + j * 16 + cc)] = acc[i][j][r];
}

// qkv fp32 [B*S][3072] -> RoPE'd Q (pre-scaled by 0.125*log2(e)), K bf16 [b,h,s,64].
// V handled by vtrans.
__global__ __launch_bounds__(256) void rope_split(const float* __restrict__ qkv,
                                                  const int* __restrict__ pos,
                                                  u16* __restrict__ Qb,
                                                  u16* __restrict__ Kb) {
    int tid = blockIdx.x * 256 + threadIdx.x;   // 0 .. 2^21-1
    int t = tid & 31;
    int h = (tid >> 5) & 15;
    int s = (tid >> 9) & 2047;
    int b = tid >> 20;
    const float* row = qkv + (size_t)((b << 11) + s) * 3072;
    float fp  = (float)pos[s];
    float inv = powf(10000.0f, -(float)(2 * t) * (1.0f / 64.0f));
    float angle = fp * inv;
    float sn, cs;
    sincosf(angle, &sn, &cs);
    int off = h * 64 + 2 * t;
    float2 q2 = *(const float2*)(row + off);
    float2 k2 = *(const float2*)(row + 1024 + off);
    size_t oidx = (((size_t)(b * 16 + h) * 2048) + s) * 64 + 2 * t;
    const float qs = 0.18033688011112042f;   // 0.125 * log2(e): exp(x) = exp2(x*log2e)
    u16x2 qo, ko;
    qo[0] = f2bf((q2.x * cs - q2.y * sn) * qs);
    qo[1] = f2bf((q2.x * sn + q2.y * cs) * qs);
    ko[0] = f2bf(k2.x * cs - k2.y * sn);
    ko[1] = f2bf(k2.x * sn + k2.y * cs);
    *(u16x2*)&Qb[oidx] = qo;
    *(u16x2*)&Kb[oidx] = ko;
}

// V-part of qkv (fp32) -> bf16 transposed: Vt[((b*16+h)*64+d)*2048 + (s/64)*64 + pos(s%64)]
// pos(k) = (k&15)*4 + (k>>4)  (the packed-P interleave, baked into global layout).
// Block = (s-tile 64) x (h) x (b); coalesced read + coalesced 16B writes.
__global__ __launch_bounds__(256) void vtrans(const float* __restrict__ qkv,
                                              u16* __restrict__ Vt) {
    __shared__ u16 lds[64][72];
    const int t = threadIdx.x;
    const int st = blockIdx.x, h = blockIdx.y, b = blockIdx.z;
    const int s0 = st << 6;
    {
        const int r = t >> 2, c0 = (t & 3) << 4;
        const float* src = qkv + (size_t)((b << 11) + s0 + r) * 3072 + 2048 + h * 64 + c0;
        const float4* p = (const float4*)src;
        #pragma unroll
        for (int q = 0; q < 4; ++q) {
            float4 v = p[q];
            lds[r][c0 + q * 4 + 0] = f2bf(v.x);
            lds[r][c0 + q * 4 + 1] = f2bf(v.y);
            lds[r][c0 + q * 4 + 2] = f2bf(v.z);
            lds[r][c0 + q * 4 + 3] = f2bf(v.w);
        }
    }
    __syncthreads();
    const size_t obase = ((size_t)((b << 4) + h) << 17) + (st << 6);
    #pragma unroll
    for (int w = 0; w < 2; ++w) {
        const int q = t + (w << 8);
        const int d = q >> 3, c = q & 7;
        u16x8 o;
        #pragma unroll
        for (int i = 0; i < 8; ++i) {
            const int p = (c << 3) + i;
            const int k = ((p & 3) << 4) + (p >> 2);   // inverse of pos()
            o[i] = lds[k][d];
        }
        *(u16x8*)(Vt + obase + ((size_t)d << 11) + (c << 3)) = o;
    }
}

// Causal flash attention, NO online max (scores bounded: |s| <= |q||k|/8 << 88).
// Block = 4 waves, each wave 16 q-rows (QBLK=64), KBLK=64.
// K/V staged by global_load_lds with pre-swizzled GLOBAL source (LDS linear):
// LDS[row][c] = global[row][c ^ s8(row)], so reads use (fo ^ swz(row)) as before.
// V comes from Vt (pre-transposed + pos-interleaved global layout).
// Block processes q-tile pair (qt, 31-qt): constant 33 K-tiles. XCD-bijective
// block swizzle puts all 16 pr-blocks of an (h,b) on one XCD (L2 reuse).
// l = sum_k P via ones-MFMA. Output bf16 [b*s][1024].
__global__ __launch_bounds__(256) void attn_causal(const u16* __restrict__ Q,
                                                   const u16* __restrict__ K,
                                                   const u16* __restrict__ Vt,
                                                   u16* __restrict__ O) {
    __shared__ u16 Ks[2][4096];    // [key][d], dbuf, source-swizzled
    __shared__ u16 Vs[2][4096];    // [d][kpos], dbuf, source-swizzled
    __shared__ u16 Ps[4][1024];    // per-wave [qrow][kpos] swizzled
    const int tid = threadIdx.x, lane = tid & 63, wave = tid >> 6;
    const int nid = ((blockIdx.x & 7) << 6) + (blockIdx.x >> 3);   // XCD-contiguous
    const int pr = nid & 15, h = (nid >> 4) & 15, b = nid >> 8;
    const int S = 2048;
    const size_t base = (size_t)((b << 4) + h) << 17;   // (b*16+h)*2048*64
    const int fr = lane & 15, fo = (lane >> 4) << 3, cr = (lane >> 4) << 2;
    const int schk = lane & 7, srow8 = lane >> 3;
    u16x8 ones_u;
    #pragma unroll
    for (int i = 0; i < 8; ++i) ones_u[i] = 0x3F80;   // bf16 1.0
    const bf16x8 ones = as_bf16x8(ones_u);

    // stage K/V tile t into buf bi: 4 glds16 per wave (8 rows each), source-swizzled
    auto stage = [&](int t, int bi) {
        #pragma unroll
        for (int g = 0; g < 2; ++g) {
            const int rg = (wave << 4) + (g << 3);       // wave-uniform row group
            const int r  = rg + srow8;                   // per-lane row / d
            const int ck = (schk ^ srow8 ^ ((wave << 1) + g)) << 3;   // s8(r)=srow8^(2w+g)
            glds16(K  + base + ((size_t)((t << 6) + r) << 6) + ck, &Ks[bi][rg << 6]);
            glds16(Vt + base + ((size_t)r << 11) + (t << 6) + ck,   &Vs[bi][rg << 6]);
        }
    };

    #pragma unroll
    for (int phase = 0; phase < 2; ++phase) {
        const int qt = phase ? (31 - pr) : pr;
        const int nkt = qt + 1;
        const int qw = (qt << 6) + (wave << 4);
        bf16x8 aq0, aq1;
        {
            const u16* qrow = Q + base + (size_t)(qw + fr) * 64;
            aq0 = as_bf16x8(*(const u16x8*)(qrow + fo));
            aq1 = as_bf16x8(*(const u16x8*)(qrow + 32 + fo));
        }
        f32x4 oacc[4] = {};
        f32x4 lacc = {};
        __syncthreads();   // prior phase's LDS readers done before overwriting buf0
        stage(0, 0);
        for (int t = 0; t < nkt; ++t) {
            __syncthreads();   // drains vmcnt: buf[t&1] ready; readers of buf[(t+1)&1] done
            if (t + 1 < nkt) stage(t + 1, (t + 1) & 1);
            const u16* Kb = &Ks[t & 1][0];
            const u16* Vb = &Vs[t & 1][0];
            const bool diag = (t == nkt - 1);
            const int nch = diag ? wave + 1 : 4;
            // QK^T (chunks of 16 keys)
            f32x4 sacc[4];
            #pragma unroll
            for (int ch = 0; ch < 4; ++ch) {
                if (ch < nch) {
                    const int r = ch * 16 + fr;
                    const int sw = swz(r);
                    bf16x8 bk0 = *(const bf16x8*)&Kb[r * 64 + (fo ^ sw)];
                    bf16x8 bk1 = *(const bf16x8*)&Kb[r * 64 + ((32 + fo) ^ sw)];
                    f32x4 sc = {};
                    sc = __builtin_amdgcn_mfma_f32_16x16x32_bf16(aq0, bk0, sc, 0, 0, 0);
                    sc = __builtin_amdgcn_mfma_f32_16x16x32_bf16(aq1, bk1, sc, 0, 0, 0);
                    sacc[ch] = sc;
                }
            }
            // exp (log2 domain) + packed b64 P write (kpos = (k&15)*4 + (k>>4))
            #pragma unroll
            for (int j = 0; j < 4; ++j) {
                const int prow = cr + j;
                u16x4 pk;
                #pragma unroll
                for (int ch = 0; ch < 4; ++ch) {
                    float e = 0.f;
                    if (ch < nch) {
                        if (!(diag && ch == wave && fr > prow)) e = exp2f(sacc[ch][j]);
                    }
                    pk[ch] = f2bf(e);
                }
                *(u16x4*)&Ps[wave][prow * 64 + ((fr << 2) ^ swz(prow))] = pk;
            }
            // PV + row-sum (ones-MFMA). Always both kk halves: interleave spreads
            // every chunk across both halves; masked entries are 0.
            #pragma unroll
            for (int kk = 0; kk < 2; ++kk) {
                const int pbase = (kk << 5) + fo;
                bf16x8 pa = *(const bf16x8*)&Ps[wave][fr * 64 + (pbase ^ swz(fr))];
                lacc = __builtin_amdgcn_mfma_f32_16x16x32_bf16(pa, ones, lacc, 0, 0, 0);
                #pragma unroll
                for (int tt = 0; tt < 4; ++tt) {
                    const int d = tt * 16 + fr;
                    bf16x8 bv = *(const bf16x8*)&Vb[d * 64 + (pbase ^ swz(d))];
                    oacc[tt] = __builtin_amdgcn_mfma_f32_16x16x32_bf16(pa, bv, oacc[tt], 0, 0, 0);
                }
            }
        }
        // epilogue: normalize and store bf16
        f32x4 inv;
        #pragma unroll
        for (int j = 0; j < 4; ++j) inv[j] = 1.f / lacc[j];
        #pragma unroll
        for (int tt = 0; tt < 4; ++tt)
            for (int j = 0; j < 4; ++j)
                O[(size_t)(b * S + qw + cr + j) * 1024 + h * 64 + tt * 16 + fr] =
                    f2bf(oacc[tt][j] * inv[j]);
    }
}

extern "C" void kernel_launch(void* const* d_in, const int* in_sizes, int n_in,
                              void* d_out, int out_size, void* d_ws, size_t ws_size,
                              hipStream_t stream) {
    const float* x     = (const float*)d_in[0];   // [2,2048,1024]
    const float* qkv_w = (const float*)d_in[1];   // [3072,1024]
    const float* out_w = (const float*)d_in[2];   // [1024,1024]
    const int*   pos   = (const int*)d_in[3];     // [2048]
    float* out = (float*)d_out;                   // [2,2048,1024] fp32

    char* ws = (char*)d_ws;
    float* qkv  = (float*)ws;                        // 50331648 B
    u16*   Qb   = (u16*)(ws + 50331648);             // 8388608 B
    u16*   Kb   = (u16*)(ws + 58720256);             // 8388608 B
    u16*   Vtg  = (u16*)(ws + 67108864);             // 8388608 B (transposed V)
    u16*   x16  = (u16*)(ws + 75497472);             // 8388608 B (reused as att16)
    u16*   att16= (u16*)(ws + 75497472);
    u16*   w16  = (u16*)(ws + 83886080);             // 6291456 B
    u16*   ow16 = (u16*)(ws + 90177536);             // 2097152 B  (total 92274688)

    // 0) fp32 -> bf16 converts
    f32bf16<<<2048, 256, 0, stream>>>(x, x16, 524288);
    f32bf16<<<1536, 256, 0, stream>>>(qkv_w, w16, 393216);
    f32bf16<<<512, 256, 0, stream>>>(out_w, ow16, 131072);
    // 1) qkv = x @ qkv_w^T : M=4096, N=3072, K=1024  (768 blocks, XCD-swizzled)
    gemm128<<<768, 256, 0, stream>>>(x16, w16, qkv, 3072, 1024, 24);
    // 2a) RoPE Q,K (Q pre-scaled by 0.125*log2e)
    rope_split<<<8192, 256, 0, stream>>>(qkv, pos, Qb, Kb);
    // 2b) V transpose + interleave -> Vtg [b,h,d, tile*64+pos]
    vtrans<<<dim3(32, 16, 2), 256, 0, stream>>>(qkv, Vtg);
    // 3) causal flash attention -> att16 bf16 [4096][1024]; 512 blocks XCD-swizzled
    attn_causal<<<512, 256, 0, stream>>>(Qb, Kb, Vtg, att16);
    // 4) out = att16 @ out_w^T : M=4096, N=1024, K=1024  (256 blocks, XCD-swizzled)
    gemm128<<<256, 256, 0, stream>>>(att16, ow16, out, 1024, 1024, 8);
}